// Round 2
// baseline (349.256 us; speedup 1.0000x reference)
//
#include <hip/hip_runtime.h>
#include <math.h>

#define BB 32
#define SS 4096
#define DD 1024
#define UU 1024

// ws layout (floats): [0..31] gauss, [32..63] rowmax, [64..95] scale = gauss/sumexp

__global__ void gauss_kernel(const float* __restrict__ query,
                             const float* __restrict__ key_lengths,
                             const float* __restrict__ Wq,
                             const float* __restrict__ wp,
                             const int* __restrict__ win,
                             float* __restrict__ wsbuf) {
    int b = blockIdx.x;
    __shared__ float q[DD];
    for (int i = threadIdx.x; i < DD; i += 256) q[i] = query[b * DD + i];
    __syncthreads();

    float partial = 0.f;
    for (int u = threadIdx.x; u < UU; u += 256) {
        float acc = 0.f;
        for (int d = 0; d < DD; ++d) acc += q[d] * Wq[d * UU + u];
        partial += tanhf(acc) * wp[u];
    }
    __shared__ float red[256];
    red[threadIdx.x] = partial;
    __syncthreads();
    for (int t = 128; t > 0; t >>= 1) {
        if (threadIdx.x < t) red[threadIdx.x] += red[threadIdx.x + t];
        __syncthreads();
    }
    if (threadIdx.x == 0) {
        float sig = 1.f / (1.f + expf(-red[0]));
        float kl = key_lengths[b];
        float pa = kl * sig;
        float w = (float)(*win);
        float std2 = (w * 0.5f) * (w * 0.5f);
        float dist = (kl - pa) * (kl - pa);
        wsbuf[b] = expf(-dist / (2.f * std2));
    }
}

// one wave per (b,s) row; 4 waves per block
__global__ void score_kernel(const float* __restrict__ query,
                             const float* __restrict__ keys,
                             float* __restrict__ scores) {
    int idx = blockIdx.x * 4 + (threadIdx.x >> 6);   // global row over B*S
    int lane = threadIdx.x & 63;
    int b = idx >> 12;                                // / SS
    int s = idx & (SS - 1);
    const float4* krow = (const float4*)(keys + ((size_t)b * SS + s) * DD);
    const float4* qrow = (const float4*)(query + (size_t)b * DD);
    float acc = 0.f;
#pragma unroll
    for (int j = 0; j < 4; ++j) {
        float4 k = krow[lane + 64 * j];
        float4 q = qrow[lane + 64 * j];
        acc += k.x * q.x + k.y * q.y + k.z * q.z + k.w * q.w;
    }
#pragma unroll
    for (int off = 32; off > 0; off >>= 1) acc += __shfl_down(acc, off, 64);
    if (lane == 0) scores[idx] = acc;
}

__global__ void stats_kernel(const float* __restrict__ scores,
                             float* __restrict__ wsbuf) {
    int b = blockIdx.x;
    const float* row = scores + (size_t)b * SS;
    __shared__ float red[256];

    float m = -INFINITY;
    for (int i = threadIdx.x; i < SS; i += 256) m = fmaxf(m, row[i]);
    red[threadIdx.x] = m;
    __syncthreads();
    for (int t = 128; t > 0; t >>= 1) {
        if (threadIdx.x < t) red[threadIdx.x] = fmaxf(red[threadIdx.x], red[threadIdx.x + t]);
        __syncthreads();
    }
    m = red[0];
    __syncthreads();

    float sum = 0.f;
    for (int i = threadIdx.x; i < SS; i += 256) sum += expf(row[i] - m);
    red[threadIdx.x] = sum;
    __syncthreads();
    for (int t = 128; t > 0; t >>= 1) {
        if (threadIdx.x < t) red[threadIdx.x] += red[threadIdx.x + t];
        __syncthreads();
    }
    if (threadIdx.x == 0) {
        wsbuf[32 + b] = m;
        wsbuf[64 + b] = wsbuf[b] / red[0];   // gauss / sumexp
    }
}

// grid (sc=32, b=32); each block: all 1024 d (float4 per thread), 128 s
__global__ void context_kernel(const float* __restrict__ keys,
                               const float* __restrict__ scores,
                               const float* __restrict__ wsbuf,
                               float* __restrict__ ctx) {
    int b = blockIdx.y;
    int sc = blockIdx.x;
    float m = wsbuf[32 + b];
    float scale = wsbuf[64 + b];
    int s0 = sc * 128;
    const float4* kbase = (const float4*)(keys + ((size_t)b * SS + s0) * DD);
    float4 acc = {0.f, 0.f, 0.f, 0.f};
    for (int i = 0; i < 128; ++i) {
        float w = expf(scores[(size_t)b * SS + s0 + i] - m) * scale;
        float4 k = kbase[(size_t)i * 256 + threadIdx.x];
        acc.x += w * k.x;
        acc.y += w * k.y;
        acc.z += w * k.z;
        acc.w += w * k.w;
    }
    float* out = ctx + (size_t)b * DD + threadIdx.x * 4;
    atomicAdd(out + 0, acc.x);
    atomicAdd(out + 1, acc.y);
    atomicAdd(out + 2, acc.z);
    atomicAdd(out + 3, acc.w);
}

extern "C" void kernel_launch(void* const* d_in, const int* in_sizes, int n_in,
                              void* d_out, int out_size, void* d_ws, size_t ws_size,
                              hipStream_t stream) {
    const float* query       = (const float*)d_in[0];
    const float* keys        = (const float*)d_in[1];
    const float* key_lengths = (const float*)d_in[2];
    const float* Wq          = (const float*)d_in[3];
    const float* wp          = (const float*)d_in[4];
    const int*   win         = (const int*)d_in[5];

    float* out    = (float*)d_out;
    float* ctx    = out;            // B*D floats
    float* scores = out + BB * DD;  // B*S floats
    float* wsbuf  = (float*)d_ws;

    hipMemsetAsync(ctx, 0, BB * DD * sizeof(float), stream);

    gauss_kernel<<<BB, 256, 0, stream>>>(query, key_lengths, Wq, wp, win, wsbuf);
    score_kernel<<<BB * SS / 4, 256, 0, stream>>>(query, keys, scores);
    stats_kernel<<<BB, 256, 0, stream>>>(scores, wsbuf);
    dim3 cgrid(SS / 128, BB);
    context_kernel<<<cgrid, 256, 0, stream>>>(keys, scores, wsbuf, ctx);
}

// Round 3
// 201.202 us; speedup vs baseline: 1.7358x; 1.7358x over previous
//
#include <hip/hip_runtime.h>
#include <math.h>

#define BB 32
#define SS 4096
#define DD 1024
#define UU 1024
#define ROWS 32            // key rows per wave
#define CH (SS / ROWS)     // 128 chunks per batch

// ws layout (floats):
//   [0..31]                      per-b pre-sigmoid accumulator (zeroed each launch)
//   [256 .. 256+BB*CH*2)         (m, l) per (b,chunk)
//   [16384 .. 16384+BB*CH*DD)    acc partials (16 MiB)

__global__ void gauss_partial(const float* __restrict__ query,
                              const float* __restrict__ Wq,
                              const float* __restrict__ wp,
                              float* __restrict__ wsbuf) {
    int b = blockIdx.x;          // grid (BB, 4)
    int u = blockIdx.y * 256 + threadIdx.x;
    __shared__ float q[DD];
    for (int i = threadIdx.x; i < DD; i += 256) q[i] = query[b * DD + i];
    __syncthreads();
    float acc = 0.f;
    for (int d = 0; d < DD; ++d) acc += q[d] * Wq[d * UU + u];
    float val = tanhf(acc) * wp[u];
    __shared__ float red[256];
    red[threadIdx.x] = val;
    __syncthreads();
    for (int t = 128; t > 0; t >>= 1) {
        if (threadIdx.x < t) red[threadIdx.x] += red[threadIdx.x + t];
        __syncthreads();
    }
    if (threadIdx.x == 0) atomicAdd(&wsbuf[b], red[0]);
}

// one wave = one chunk of ROWS key rows; online softmax + weighted accumulate
__global__ __launch_bounds__(256) void flash_kernel(const float* __restrict__ query,
                                                    const float* __restrict__ keys,
                                                    float* __restrict__ scores,
                                                    float* __restrict__ mlbuf,
                                                    float* __restrict__ accbuf) {
    int w = blockIdx.x * 4 + (threadIdx.x >> 6);
    int lane = threadIdx.x & 63;
    int b = w >> 7;              // / CH
    int chunk = w & (CH - 1);
    int s0 = chunk * ROWS;

    const float4* qv = (const float4*)(query + (size_t)b * DD);
    float4 q0 = qv[lane], q1 = qv[lane + 64], q2 = qv[lane + 128], q3 = qv[lane + 192];

    const float4* kbase = (const float4*)(keys + ((size_t)b * SS + s0) * DD);
    float4 a0 = {0,0,0,0}, a1 = {0,0,0,0}, a2 = {0,0,0,0}, a3 = {0,0,0,0};
    float m = -INFINITY, l = 0.f;

    for (int i = 0; i < ROWS; ++i) {
        const float4* kr = kbase + (size_t)i * 256;
        float4 k0 = kr[lane], k1 = kr[lane + 64], k2 = kr[lane + 128], k3 = kr[lane + 192];
        float d = k0.x*q0.x + k0.y*q0.y + k0.z*q0.z + k0.w*q0.w;
        d += k1.x*q1.x + k1.y*q1.y + k1.z*q1.z + k1.w*q1.w;
        d += k2.x*q2.x + k2.y*q2.y + k2.z*q2.z + k2.w*q2.w;
        d += k3.x*q3.x + k3.y*q3.y + k3.z*q3.z + k3.w*q3.w;
#pragma unroll
        for (int off = 32; off > 0; off >>= 1) d += __shfl_xor(d, off, 64);
        if (lane == 0) scores[(size_t)b * SS + s0 + i] = d;

        float mn = fmaxf(m, d);
        float corr = expf(m - mn);      // exp(-inf)=0 handles first iter
        float p = expf(d - mn);
        l = l * corr + p;
        a0.x = a0.x*corr + p*k0.x; a0.y = a0.y*corr + p*k0.y; a0.z = a0.z*corr + p*k0.z; a0.w = a0.w*corr + p*k0.w;
        a1.x = a1.x*corr + p*k1.x; a1.y = a1.y*corr + p*k1.y; a1.z = a1.z*corr + p*k1.z; a1.w = a1.w*corr + p*k1.w;
        a2.x = a2.x*corr + p*k2.x; a2.y = a2.y*corr + p*k2.y; a2.z = a2.z*corr + p*k2.z; a2.w = a2.w*corr + p*k2.w;
        a3.x = a3.x*corr + p*k3.x; a3.y = a3.y*corr + p*k3.y; a3.z = a3.z*corr + p*k3.z; a3.w = a3.w*corr + p*k3.w;
        m = mn;
    }

    int pidx = b * CH + chunk;
    if (lane == 0) { mlbuf[pidx * 2] = m; mlbuf[pidx * 2 + 1] = l; }
    float4* ab = (float4*)(accbuf + (size_t)pidx * DD);
    ab[lane] = a0; ab[lane + 64] = a1; ab[lane + 128] = a2; ab[lane + 192] = a3;
}

__global__ void combine_kernel(const float* __restrict__ mlbuf,
                               const float* __restrict__ accbuf,
                               const float* __restrict__ wsbuf,
                               const float* __restrict__ key_lengths,
                               const int* __restrict__ win,
                               float* __restrict__ ctx) {
    int b = blockIdx.x;          // grid (BB, 4)
    int d = blockIdx.y * 256 + threadIdx.x;

    __shared__ float mv[CH], lv[CH], wexp[CH];
    if (threadIdx.x < CH) {
        mv[threadIdx.x] = mlbuf[(b * CH + threadIdx.x) * 2];
        lv[threadIdx.x] = mlbuf[(b * CH + threadIdx.x) * 2 + 1];
    }
    __syncthreads();
    float M = -INFINITY;
    for (int i = 0; i < CH; ++i) M = fmaxf(M, mv[i]);
    float L = 0.f;
    for (int i = 0; i < CH; ++i) L += lv[i] * expf(mv[i] - M);
    __syncthreads();
    if (threadIdx.x < CH) wexp[threadIdx.x] = expf(mv[threadIdx.x] - M);
    __syncthreads();

    float acc = 0.f;
    for (int i = 0; i < CH; ++i)
        acc += wexp[i] * accbuf[((size_t)b * CH + i) * DD + d];

    float sig = 1.f / (1.f + expf(-wsbuf[b]));
    float kl = key_lengths[b];
    float pa = kl * sig;
    float wv = (float)(*win);
    float std2 = (wv * 0.5f) * (wv * 0.5f);
    float g = expf(-((kl - pa) * (kl - pa)) / (2.f * std2));

    ctx[(size_t)b * DD + d] = acc * g / L;
}

extern "C" void kernel_launch(void* const* d_in, const int* in_sizes, int n_in,
                              void* d_out, int out_size, void* d_ws, size_t ws_size,
                              hipStream_t stream) {
    const float* query       = (const float*)d_in[0];
    const float* keys        = (const float*)d_in[1];
    const float* key_lengths = (const float*)d_in[2];
    const float* Wq          = (const float*)d_in[3];
    const float* wp          = (const float*)d_in[4];
    const int*   win         = (const int*)d_in[5];

    float* out    = (float*)d_out;
    float* ctx    = out;            // B*D floats
    float* scores = out + BB * DD;  // B*S floats
    float* wsbuf  = (float*)d_ws;
    float* mlbuf  = wsbuf + 256;
    float* accbuf = wsbuf + 16384;

    hipMemsetAsync(wsbuf, 0, BB * sizeof(float), stream);

    dim3 ggrid(BB, UU / 256);
    gauss_partial<<<ggrid, 256, 0, stream>>>(query, Wq, wp, wsbuf);

    flash_kernel<<<BB * CH / 4, 256, 0, stream>>>(query, keys, scores, mlbuf, accbuf);

    dim3 cgrid(BB, DD / 256);
    combine_kernel<<<cgrid, 256, 0, stream>>>(mlbuf, accbuf, wsbuf, key_lengths, win, ctx);
}

// Round 4
// 178.647 us; speedup vs baseline: 1.9550x; 1.1263x over previous
//
#include <hip/hip_runtime.h>
#include <math.h>

#define BB 32
#define SS 4096
#define DD 1024
#define UU 1024
#define ROWS 32            // key rows per wave (16 per chain)
#define CH (SS / ROWS)     // 128 chunks per batch
#define FBLK (BB * CH / 4) // 1024 flash blocks
#define GBLK (BB * 4)      // 128 gauss blocks

// ws layout (floats):
//   [0..31]                      per-b pre-sigmoid accumulator (zeroed each launch)
//   [256 .. 256+BB*CH*2)         (m, l) per (b,chunk)
//   [16384 .. 16384+BB*CH*DD)    acc partials (16 MiB)

__global__ __launch_bounds__(256) void fused_kernel(const float* __restrict__ query,
                                                    const float* __restrict__ keys,
                                                    const float* __restrict__ Wq,
                                                    const float* __restrict__ wp,
                                                    float* __restrict__ scores,
                                                    float* __restrict__ mlbuf,
                                                    float* __restrict__ accbuf,
                                                    float* __restrict__ gaccum) {
    if (blockIdx.x >= FBLK) {
        // ---- gauss specialization: 128 blocks compute pre-sigmoid scalar ----
        int gb = blockIdx.x - FBLK;
        int b = gb >> 2;
        int u = (gb & 3) * 256 + threadIdx.x;
        __shared__ float q[DD];
        for (int i = threadIdx.x; i < DD; i += 256) q[i] = query[b * DD + i];
        __syncthreads();
        float acc = 0.f;
#pragma unroll 8
        for (int d = 0; d < DD; ++d) acc += q[d] * Wq[d * UU + u];
        float val = tanhf(acc) * wp[u];
        __shared__ float red[256];
        red[threadIdx.x] = val;
        __syncthreads();
        for (int t = 128; t > 0; t >>= 1) {
            if (threadIdx.x < t) red[threadIdx.x] += red[threadIdx.x + t];
            __syncthreads();
        }
        if (threadIdx.x == 0) atomicAdd(&gaccum[b], red[0]);
        return;
    }

    // ---- flash: one wave = 32 key rows as two independent 16-row chains ----
    int w = blockIdx.x * 4 + (threadIdx.x >> 6);
    int lane = threadIdx.x & 63;
    int b = w >> 7;              // / CH
    int chunk = w & (CH - 1);
    int s0 = chunk * ROWS;

    const float4* qv = (const float4*)(query + (size_t)b * DD);
    float4 q0 = qv[lane], q1 = qv[lane + 64], q2 = qv[lane + 128], q3 = qv[lane + 192];

    const float4* kbase = (const float4*)(keys + ((size_t)b * SS + s0) * DD);
    float4 A0 = {0,0,0,0}, A1 = {0,0,0,0}, A2 = {0,0,0,0}, A3 = {0,0,0,0};
    float4 B0 = {0,0,0,0}, B1 = {0,0,0,0}, B2 = {0,0,0,0}, B3 = {0,0,0,0};
    float mA = -INFINITY, lA = 0.f, mB = -INFINITY, lB = 0.f;

    for (int i = 0; i < ROWS / 2; ++i) {
        const float4* krA = kbase + (size_t)i * 256;
        const float4* krB = kbase + (size_t)(i + 16) * 256;
        float4 kA0 = krA[lane], kA1 = krA[lane + 64], kA2 = krA[lane + 128], kA3 = krA[lane + 192];
        float4 kB0 = krB[lane], kB1 = krB[lane + 64], kB2 = krB[lane + 128], kB3 = krB[lane + 192];

        float dA = kA0.x*q0.x + kA0.y*q0.y + kA0.z*q0.z + kA0.w*q0.w
                 + kA1.x*q1.x + kA1.y*q1.y + kA1.z*q1.z + kA1.w*q1.w
                 + kA2.x*q2.x + kA2.y*q2.y + kA2.z*q2.z + kA2.w*q2.w
                 + kA3.x*q3.x + kA3.y*q3.y + kA3.z*q3.z + kA3.w*q3.w;
        float dB = kB0.x*q0.x + kB0.y*q0.y + kB0.z*q0.z + kB0.w*q0.w
                 + kB1.x*q1.x + kB1.y*q1.y + kB1.z*q1.z + kB1.w*q1.w
                 + kB2.x*q2.x + kB2.y*q2.y + kB2.z*q2.z + kB2.w*q2.w
                 + kB3.x*q3.x + kB3.y*q3.y + kB3.z*q3.z + kB3.w*q3.w;
#pragma unroll
        for (int off = 32; off > 0; off >>= 1) {
            dA += __shfl_xor(dA, off, 64);
            dB += __shfl_xor(dB, off, 64);
        }
        if (lane == 0) {
            scores[(size_t)b * SS + s0 + i] = dA;
            scores[(size_t)b * SS + s0 + 16 + i] = dB;
        }

        float mnA = fmaxf(mA, dA);
        float cA = __expf(mA - mnA);
        float pA = __expf(dA - mnA);
        lA = lA * cA + pA;
        A0.x = A0.x*cA + pA*kA0.x; A0.y = A0.y*cA + pA*kA0.y; A0.z = A0.z*cA + pA*kA0.z; A0.w = A0.w*cA + pA*kA0.w;
        A1.x = A1.x*cA + pA*kA1.x; A1.y = A1.y*cA + pA*kA1.y; A1.z = A1.z*cA + pA*kA1.z; A1.w = A1.w*cA + pA*kA1.w;
        A2.x = A2.x*cA + pA*kA2.x; A2.y = A2.y*cA + pA*kA2.y; A2.z = A2.z*cA + pA*kA2.z; A2.w = A2.w*cA + pA*kA2.w;
        A3.x = A3.x*cA + pA*kA3.x; A3.y = A3.y*cA + pA*kA3.y; A3.z = A3.z*cA + pA*kA3.z; A3.w = A3.w*cA + pA*kA3.w;
        mA = mnA;

        float mnB = fmaxf(mB, dB);
        float cB = __expf(mB - mnB);
        float pB = __expf(dB - mnB);
        lB = lB * cB + pB;
        B0.x = B0.x*cB + pB*kB0.x; B0.y = B0.y*cB + pB*kB0.y; B0.z = B0.z*cB + pB*kB0.z; B0.w = B0.w*cB + pB*kB0.w;
        B1.x = B1.x*cB + pB*kB1.x; B1.y = B1.y*cB + pB*kB1.y; B1.z = B1.z*cB + pB*kB1.z; B1.w = B1.w*cB + pB*kB1.w;
        B2.x = B2.x*cB + pB*kB2.x; B2.y = B2.y*cB + pB*kB2.y; B2.z = B2.z*cB + pB*kB2.z; B2.w = B2.w*cB + pB*kB2.w;
        B3.x = B3.x*cB + pB*kB3.x; B3.y = B3.y*cB + pB*kB3.y; B3.z = B3.z*cB + pB*kB3.z; B3.w = B3.w*cB + pB*kB3.w;
        mB = mnB;
    }

    // merge the two chains
    float m = fmaxf(mA, mB);
    float eA = __expf(mA - m), eB = __expf(mB - m);
    float l = lA * eA + lB * eB;
    float4 a0, a1, a2, a3;
    a0.x = A0.x*eA + B0.x*eB; a0.y = A0.y*eA + B0.y*eB; a0.z = A0.z*eA + B0.z*eB; a0.w = A0.w*eA + B0.w*eB;
    a1.x = A1.x*eA + B1.x*eB; a1.y = A1.y*eA + B1.y*eB; a1.z = A1.z*eA + B1.z*eB; a1.w = A1.w*eA + B1.w*eB;
    a2.x = A2.x*eA + B2.x*eB; a2.y = A2.y*eA + B2.y*eB; a2.z = A2.z*eA + B2.z*eB; a2.w = A2.w*eA + B2.w*eB;
    a3.x = A3.x*eA + B3.x*eB; a3.y = A3.y*eA + B3.y*eB; a3.z = A3.z*eA + B3.z*eB; a3.w = A3.w*eA + B3.w*eB;

    int pidx = b * CH + chunk;
    if (lane == 0) { mlbuf[pidx * 2] = m; mlbuf[pidx * 2 + 1] = l; }
    float4* ab = (float4*)(accbuf + (size_t)pidx * DD);
    ab[lane] = a0; ab[lane + 64] = a1; ab[lane + 128] = a2; ab[lane + 192] = a3;
}

__global__ void combine_kernel(const float* __restrict__ mlbuf,
                               const float* __restrict__ accbuf,
                               const float* __restrict__ wsbuf,
                               const float* __restrict__ key_lengths,
                               const int* __restrict__ win,
                               float* __restrict__ ctx) {
    int b = blockIdx.x;          // grid (BB, 4)
    int d = blockIdx.y * 256 + threadIdx.x;

    __shared__ float mv[CH], lv[CH], wexp[CH];
    if (threadIdx.x < CH) {
        mv[threadIdx.x] = mlbuf[(b * CH + threadIdx.x) * 2];
        lv[threadIdx.x] = mlbuf[(b * CH + threadIdx.x) * 2 + 1];
    }
    __syncthreads();
    float M = -INFINITY;
    for (int i = 0; i < CH; ++i) M = fmaxf(M, mv[i]);
    float L = 0.f;
    for (int i = 0; i < CH; ++i) L += lv[i] * __expf(mv[i] - M);
    __syncthreads();
    if (threadIdx.x < CH) wexp[threadIdx.x] = __expf(mv[threadIdx.x] - M);
    __syncthreads();

    float acc = 0.f;
#pragma unroll 8
    for (int i = 0; i < CH; ++i)
        acc += wexp[i] * accbuf[((size_t)b * CH + i) * DD + d];

    float sig = 1.f / (1.f + __expf(-wsbuf[b]));
    float kl = key_lengths[b];
    float pa = kl * sig;
    float wv = (float)(*win);
    float std2 = (wv * 0.5f) * (wv * 0.5f);
    float g = __expf(-((kl - pa) * (kl - pa)) / (2.f * std2));

    ctx[(size_t)b * DD + d] = acc * g / L;
}

extern "C" void kernel_launch(void* const* d_in, const int* in_sizes, int n_in,
                              void* d_out, int out_size, void* d_ws, size_t ws_size,
                              hipStream_t stream) {
    const float* query       = (const float*)d_in[0];
    const float* keys        = (const float*)d_in[1];
    const float* key_lengths = (const float*)d_in[2];
    const float* Wq          = (const float*)d_in[3];
    const float* wp          = (const float*)d_in[4];
    const int*   win         = (const int*)d_in[5];

    float* out    = (float*)d_out;
    float* ctx    = out;            // B*D floats
    float* scores = out + BB * DD;  // B*S floats
    float* wsbuf  = (float*)d_ws;
    float* mlbuf  = wsbuf + 256;
    float* accbuf = wsbuf + 16384;

    hipMemsetAsync(wsbuf, 0, BB * sizeof(float), stream);

    fused_kernel<<<FBLK + GBLK, 256, 0, stream>>>(query, keys, Wq, wp,
                                                  scores, mlbuf, accbuf, wsbuf);

    dim3 cgrid(BB, DD / 256);
    combine_kernel<<<cgrid, 256, 0, stream>>>(mlbuf, accbuf, wsbuf, key_lengths, win, ctx);
}

// Round 5
// 158.465 us; speedup vs baseline: 2.2040x; 1.1274x over previous
//
#include <hip/hip_runtime.h>
#include <math.h>

#define BB 32
#define SS 4096
#define DD 1024
#define UU 1024
#define CHROWS 64              // key rows per block
#define CH (SS / CHROWS)       // 64 chunks per batch
#define FBLK (BB * CH)         // 2048 flash blocks
#define GBLK (BB * 4)          // 128 gauss blocks (dispatched first)

// ws layout (floats):
//   [0..31]                      per-b pre-sigmoid accumulator (zeroed each launch)
//   [256 .. 256+BB*CH*2)         (m, l) per (b,chunk)
//   [16384 .. 16384+BB*CH*DD)    acc partials (8 MiB)

__global__ __launch_bounds__(256) void fused_kernel(const float* __restrict__ query,
                                                    const float* __restrict__ keys,
                                                    const float* __restrict__ Wq,
                                                    const float* __restrict__ wp,
                                                    float* __restrict__ scores,
                                                    float* __restrict__ mlbuf,
                                                    float* __restrict__ accbuf,
                                                    float* __restrict__ gaccum) {
    if (blockIdx.x < GBLK) {
        // ---- gauss specialization: 128 blocks compute pre-sigmoid scalar ----
        int gb = blockIdx.x;
        int b = gb >> 2;
        int u = (gb & 3) * 256 + threadIdx.x;
        __shared__ float q[DD];
        for (int i = threadIdx.x; i < DD; i += 256) q[i] = query[b * DD + i];
        __syncthreads();
        float acc = 0.f;
#pragma unroll 8
        for (int d = 0; d < DD; ++d) acc += q[d] * Wq[d * UU + u];
        float val = tanhf(acc) * wp[u];
        __shared__ float red[256];
        red[threadIdx.x] = val;
        __syncthreads();
        for (int t = 128; t > 0; t >>= 1) {
            if (threadIdx.x < t) red[threadIdx.x] += red[threadIdx.x + t];
            __syncthreads();
        }
        if (threadIdx.x == 0) atomicAdd(&gaccum[b], red[0]);
        return;
    }

    // ---- flash: block = 64-row chunk; wave w owns dims [256w, 256w+256) ----
    int fb = blockIdx.x - GBLK;
    int b = fb >> 6;               // / CH
    int chunk = fb & (CH - 1);
    int s0 = chunk * CHROWS;
    int w = threadIdx.x >> 6;
    int lane = threadIdx.x & 63;
    int off = w * 64 + lane;       // float4 index within a 1024-f row

    const float4* K4 = (const float4*)keys;
    const float4* Q4 = (const float4*)query;
    float4 q4 = Q4[b * 256 + off];

    size_t rowbase = ((size_t)b * SS + s0) * 256;   // float4 units
    float4 acc = {0.f, 0.f, 0.f, 0.f};
    float m = -INFINITY, l = 0.f;

    __shared__ float part[2][8][4];

    for (int t = 0; t < CHROWS / 8; ++t) {
        float4 kr[8];
        size_t base = rowbase + (size_t)t * 8 * 256 + off;
#pragma unroll
        for (int r = 0; r < 8; ++r) kr[r] = K4[base + (size_t)r * 256];

        float s[8];
#pragma unroll
        for (int r = 0; r < 8; ++r) {
            s[r] = kr[r].x*q4.x + kr[r].y*q4.y + kr[r].z*q4.z + kr[r].w*q4.w;
#pragma unroll
            for (int o = 32; o > 0; o >>= 1) s[r] += __shfl_xor(s[r], o, 64);
        }

        int buf = t & 1;
        if (lane == 0) {
#pragma unroll
            for (int r = 0; r < 8; ++r) part[buf][r][w] = s[r];
        }
        __syncthreads();

        float rs[8];
#pragma unroll
        for (int r = 0; r < 8; ++r)
            rs[r] = part[buf][r][0] + part[buf][r][1] + part[buf][r][2] + part[buf][r][3];

#pragma unroll
        for (int r = 0; r < 8; ++r)
            if (threadIdx.x == r) scores[(size_t)b * SS + s0 + t * 8 + r] = rs[r];

        // amortized online softmax (uniform across block)
        float tm = rs[0];
#pragma unroll
        for (int r = 1; r < 8; ++r) tm = fmaxf(tm, rs[r]);
        float mn = fmaxf(m, tm);
        float corr = __expf(m - mn);    // exp(-inf)=0 handles first tile
        float p[8]; float ps = 0.f;
#pragma unroll
        for (int r = 0; r < 8; ++r) { p[r] = __expf(rs[r] - mn); ps += p[r]; }
        l = l * corr + ps;
        m = mn;
        acc.x *= corr; acc.y *= corr; acc.z *= corr; acc.w *= corr;
#pragma unroll
        for (int r = 0; r < 8; ++r) {
            acc.x += p[r] * kr[r].x; acc.y += p[r] * kr[r].y;
            acc.z += p[r] * kr[r].z; acc.w += p[r] * kr[r].w;
        }
    }

    int pidx = b * CH + chunk;
    if (threadIdx.x == 0) { mlbuf[pidx * 2] = m; mlbuf[pidx * 2 + 1] = l; }
    float4* ab = (float4*)(accbuf + (size_t)pidx * DD);
    ab[off] = acc;
}

__global__ void combine_kernel(const float* __restrict__ mlbuf,
                               const float* __restrict__ accbuf,
                               const float* __restrict__ wsbuf,
                               const float* __restrict__ key_lengths,
                               const int* __restrict__ win,
                               float* __restrict__ ctx) {
    int b = blockIdx.x;          // grid (BB, 4)
    int d = blockIdx.y * 256 + threadIdx.x;

    __shared__ float mv[CH], lv[CH], wexp[CH];
    if (threadIdx.x < CH) {
        mv[threadIdx.x] = mlbuf[(b * CH + threadIdx.x) * 2];
        lv[threadIdx.x] = mlbuf[(b * CH + threadIdx.x) * 2 + 1];
    }
    __syncthreads();
    float M = -INFINITY;
    for (int i = 0; i < CH; ++i) M = fmaxf(M, mv[i]);
    float L = 0.f;
    for (int i = 0; i < CH; ++i) L += lv[i] * __expf(mv[i] - M);
    __syncthreads();
    if (threadIdx.x < CH) wexp[threadIdx.x] = __expf(mv[threadIdx.x] - M);
    __syncthreads();

    float acc = 0.f;
#pragma unroll 8
    for (int i = 0; i < CH; ++i)
        acc += wexp[i] * accbuf[((size_t)b * CH + i) * DD + d];

    float sig = 1.f / (1.f + __expf(-wsbuf[b]));
    float kl = key_lengths[b];
    float pa = kl * sig;
    float wv = (float)(*win);
    float std2 = (wv * 0.5f) * (wv * 0.5f);
    float g = __expf(-((kl - pa) * (kl - pa)) / (2.f * std2));

    ctx[(size_t)b * DD + d] = acc * g / L;
}

extern "C" void kernel_launch(void* const* d_in, const int* in_sizes, int n_in,
                              void* d_out, int out_size, void* d_ws, size_t ws_size,
                              hipStream_t stream) {
    const float* query       = (const float*)d_in[0];
    const float* keys        = (const float*)d_in[1];
    const float* key_lengths = (const float*)d_in[2];
    const float* Wq          = (const float*)d_in[3];
    const float* wp          = (const float*)d_in[4];
    const int*   win         = (const int*)d_in[5];

    float* out    = (float*)d_out;
    float* ctx    = out;            // B*D floats
    float* scores = out + BB * DD;  // B*S floats
    float* wsbuf  = (float*)d_ws;
    float* mlbuf  = wsbuf + 256;
    float* accbuf = wsbuf + 16384;

    hipMemsetAsync(wsbuf, 0, BB * sizeof(float), stream);

    fused_kernel<<<FBLK + GBLK, 256, 0, stream>>>(query, keys, Wq, wp,
                                                  scores, mlbuf, accbuf, wsbuf);

    dim3 cgrid(BB, DD / 256);
    combine_kernel<<<cgrid, 256, 0, stream>>>(mlbuf, accbuf, wsbuf, key_lengths, win, ctx);
}

// Round 6
// 142.897 us; speedup vs baseline: 2.4441x; 1.1089x over previous
//
#include <hip/hip_runtime.h>
#include <math.h>

#define BB 32
#define SS 4096
#define DD 1024
#define UU 1024
#define TROWS 4                 // rows per tile (one per wave)
#define CHROWS 128              // rows per block
#define NT (CHROWS / TROWS)     // 32 tiles per block
#define CHB (SS / CHROWS)       // 32 chunks per batch
#define FBLK (BB * CHB)         // 1024 flash blocks
#define GBLK (BB * 4)           // 128 gauss blocks (dispatched first)
#define NPART (CHB * 4)         // 128 partials per batch (one per wave)

#define LOAD_LDS16(g, l) __builtin_amdgcn_global_load_lds( \
    (const __attribute__((address_space(1))) unsigned int*)(g), \
    (__attribute__((address_space(3))) unsigned int*)(l), 16, 0, 0)

// ws layout (floats):
//   [0..31]                      per-b pre-sigmoid accumulator (zeroed each launch)
//   [256 .. 256+BB*NPART*2)      (m, l) per partial
//   [16384 .. 16384+BB*NPART*DD) acc partials (16 MiB)

__global__ __launch_bounds__(256, 5) void fused_kernel(const float* __restrict__ query,
                                                       const float* __restrict__ keys,
                                                       const float* __restrict__ Wq,
                                                       const float* __restrict__ wp,
                                                       float* __restrict__ scores,
                                                       float* __restrict__ mlbuf,
                                                       float* __restrict__ accbuf,
                                                       float* __restrict__ gaccum) {
    __shared__ float smem[8192];   // 32 KB: flash = 2 x 16KB K-tiles; gauss overlays

    if (blockIdx.x < GBLK) {
        // ---- gauss specialization: 128 blocks compute pre-sigmoid scalar ----
        int gb = blockIdx.x;
        int b = gb >> 2;
        int u = (gb & 3) * 256 + threadIdx.x;
        float* q = smem;            // [0..1023]
        float* red = smem + 1024;   // [1024..1279]
        for (int i = threadIdx.x; i < DD; i += 256) q[i] = query[b * DD + i];
        __syncthreads();
        float acc = 0.f;
#pragma unroll 8
        for (int d = 0; d < DD; ++d) acc += q[d] * Wq[d * UU + u];
        float val = tanhf(acc) * wp[u];
        red[threadIdx.x] = val;
        __syncthreads();
        for (int t = 128; t > 0; t >>= 1) {
            if (threadIdx.x < t) red[threadIdx.x] += red[threadIdx.x + t];
            __syncthreads();
        }
        if (threadIdx.x == 0) atomicAdd(&gaccum[b], red[0]);
        return;
    }

    // ---- flash: block = 128-row chunk; wave w owns row (4t + w), full 1024 d ----
    int fb = blockIdx.x - GBLK;
    int b = fb >> 5;               // / CHB
    int chunk = fb & (CHB - 1);
    int s0 = chunk * CHROWS;
    int w = threadIdx.x >> 6;
    int lane = threadIdx.x & 63;
    int tid = threadIdx.x;

    const float4* Q4 = (const float4*)query;
    float4 q0 = Q4[b * 256 + lane],       q1 = Q4[b * 256 + lane + 64],
           q2 = Q4[b * 256 + lane + 128], q3 = Q4[b * 256 + lane + 192];

    const char* gbase = (const char*)(keys + ((size_t)b * SS + s0) * DD);
    float4 a0 = {0,0,0,0}, a1 = {0,0,0,0}, a2 = {0,0,0,0}, a3 = {0,0,0,0};
    float m = -INFINITY, l = 0.f;

    // prologue: stage tile 0 into buffer 0 (16 KB; chunk j == row j, linear)
#pragma unroll
    for (int j = 0; j < 4; ++j)
        LOAD_LDS16(gbase + j * 4096 + tid * 16, (char*)smem + j * 4096 + tid * 16);

    int bf = 0;
    for (int t = 0; t < NT; ++t) {
        if (t + 1 < NT) {
            const char* gt = gbase + (size_t)(t + 1) * 16384;
            char* lb = (char*)smem + (bf ^ 1) * 16384;
#pragma unroll
            for (int j = 0; j < 4; ++j)
                LOAD_LDS16(gt + j * 4096 + tid * 16, lb + j * 4096 + tid * 16);
            asm volatile("s_waitcnt vmcnt(4)" ::: "memory");   // tile t landed; t+1 in flight
        } else {
            asm volatile("s_waitcnt vmcnt(0)" ::: "memory");
        }
        __builtin_amdgcn_s_barrier();                           // B1: tile t ready (all waves)

        // wave w's row of this tile, from LDS (consecutive-lane b128, conflict-free)
        const float* rowp = smem + bf * 4096 + w * 1024;
        float4 k0 = *(const float4*)(rowp + (lane)        * 4);
        float4 k1 = *(const float4*)(rowp + (lane + 64)   * 4);
        float4 k2 = *(const float4*)(rowp + (lane + 128)  * 4);
        float4 k3 = *(const float4*)(rowp + (lane + 192)  * 4);

        float d = k0.x*q0.x + k0.y*q0.y + k0.z*q0.z + k0.w*q0.w
                + k1.x*q1.x + k1.y*q1.y + k1.z*q1.z + k1.w*q1.w
                + k2.x*q2.x + k2.y*q2.y + k2.z*q2.z + k2.w*q2.w
                + k3.x*q3.x + k3.y*q3.y + k3.z*q3.z + k3.w*q3.w;
#pragma unroll
        for (int o = 32; o > 0; o >>= 1) d += __shfl_xor(d, o, 64);

        if (lane == 0) scores[(size_t)b * SS + s0 + t * TROWS + w] = d;

        float mn = fmaxf(m, d);
        float corr = __expf(m - mn);   // exp(-inf) = 0 handles first tile
        float p = __expf(d - mn);
        l = l * corr + p;
        a0.x = a0.x*corr + p*k0.x; a0.y = a0.y*corr + p*k0.y; a0.z = a0.z*corr + p*k0.z; a0.w = a0.w*corr + p*k0.w;
        a1.x = a1.x*corr + p*k1.x; a1.y = a1.y*corr + p*k1.y; a1.z = a1.z*corr + p*k1.z; a1.w = a1.w*corr + p*k1.w;
        a2.x = a2.x*corr + p*k2.x; a2.y = a2.y*corr + p*k2.y; a2.z = a2.z*corr + p*k2.z; a2.w = a2.w*corr + p*k2.w;
        a3.x = a3.x*corr + p*k3.x; a3.y = a3.y*corr + p*k3.y; a3.z = a3.z*corr + p*k3.z; a3.w = a3.w*corr + p*k3.w;
        m = mn;

        __builtin_amdgcn_s_barrier();  // B2: release buf before next iter's stage overwrites
        bf ^= 1;
    }

    int pidx = fb * 4 + w;             // = b*NPART + chunk*4 + w
    if (lane == 0) { mlbuf[pidx * 2] = m; mlbuf[pidx * 2 + 1] = l; }
    float4* ab = (float4*)(accbuf + (size_t)pidx * DD);
    ab[lane] = a0; ab[lane + 64] = a1; ab[lane + 128] = a2; ab[lane + 192] = a3;
}

__global__ void combine_kernel(const float* __restrict__ mlbuf,
                               const float* __restrict__ accbuf,
                               const float* __restrict__ wsbuf,
                               const float* __restrict__ key_lengths,
                               const int* __restrict__ win,
                               float* __restrict__ ctx) {
    int b = blockIdx.x;          // grid (BB, 4)
    int d = blockIdx.y * 256 + threadIdx.x;

    __shared__ float mv[NPART], lv[NPART], wexp[NPART];
    if (threadIdx.x < NPART) {
        mv[threadIdx.x] = mlbuf[(b * NPART + threadIdx.x) * 2];
        lv[threadIdx.x] = mlbuf[(b * NPART + threadIdx.x) * 2 + 1];
    }
    __syncthreads();
    float M = -INFINITY;
    for (int i = 0; i < NPART; ++i) M = fmaxf(M, mv[i]);
    float L = 0.f;
    for (int i = 0; i < NPART; ++i) L += lv[i] * __expf(mv[i] - M);
    __syncthreads();
    if (threadIdx.x < NPART) wexp[threadIdx.x] = __expf(mv[threadIdx.x] - M);
    __syncthreads();

    float acc = 0.f;
#pragma unroll 8
    for (int i = 0; i < NPART; ++i)
        acc += wexp[i] * accbuf[((size_t)b * NPART + i) * DD + d];

    float sig = 1.f / (1.f + __expf(-wsbuf[b]));
    float kl = key_lengths[b];
    float pa = kl * sig;
    float wv = (float)(*win);
    float std2 = (wv * 0.5f) * (wv * 0.5f);
    float g = __expf(-((kl - pa) * (kl - pa)) / (2.f * std2));

    ctx[(size_t)b * DD + d] = acc * g / L;
}

extern "C" void kernel_launch(void* const* d_in, const int* in_sizes, int n_in,
                              void* d_out, int out_size, void* d_ws, size_t ws_size,
                              hipStream_t stream) {
    const float* query       = (const float*)d_in[0];
    const float* keys        = (const float*)d_in[1];
    const float* key_lengths = (const float*)d_in[2];
    const float* Wq          = (const float*)d_in[3];
    const float* wp          = (const float*)d_in[4];
    const int*   win         = (const int*)d_in[5];

    float* out    = (float*)d_out;
    float* ctx    = out;            // B*D floats
    float* scores = out + BB * DD;  // B*S floats
    float* wsbuf  = (float*)d_ws;
    float* mlbuf  = wsbuf + 256;
    float* accbuf = wsbuf + 16384;

    hipMemsetAsync(wsbuf, 0, BB * sizeof(float), stream);

    fused_kernel<<<FBLK + GBLK, 256, 0, stream>>>(query, keys, Wq, wp,
                                                  scores, mlbuf, accbuf, wsbuf);

    dim3 cgrid(BB, DD / 256);
    combine_kernel<<<cgrid, 256, 0, stream>>>(mlbuf, accbuf, wsbuf, key_lengths, win, ctx);
}

// Round 7
// 130.181 us; speedup vs baseline: 2.6829x; 1.0977x over previous
//
#include <hip/hip_runtime.h>
#include <math.h>

#define BB 32
#define SS 4096
#define DD 1024
#define UU 1024
#define TROWS 4                 // rows per tile (one per wave)
#define CHROWS 128              // rows per block
#define NT (CHROWS / TROWS)     // 32 tiles per block
#define CHB (SS / CHROWS)       // 32 chunks per batch
#define FBLK (BB * CHB)         // 1024 flash blocks
#define GBLK 128                // gauss blocks (u-slices, dispatched first)
#define NPART CHB               // 32 partials per batch (one per block)

#define LOAD_LDS16(g, l) __builtin_amdgcn_global_load_lds( \
    (const __attribute__((address_space(1))) unsigned int*)(g), \
    (__attribute__((address_space(3))) unsigned int*)(l), 16, 0, 0)

// ws layout (floats):
//   [0 .. 4096)        gpart: per (b, gauss-block) pre-sigmoid partials (b*128+g)
//   [4096 .. 6144)     (m, l) per flash partial (FBLK*2)
//   [8192 .. 8192+FBLK*DD)  acc partials (4 MiB)

__global__ __launch_bounds__(256, 5) void fused_kernel(const float* __restrict__ query,
                                                       const float* __restrict__ keys,
                                                       const float* __restrict__ Wq,
                                                       const float* __restrict__ wp,
                                                       float* __restrict__ scores,
                                                       float* __restrict__ mlbuf,
                                                       float* __restrict__ accbuf,
                                                       float* __restrict__ gpart) {
    __shared__ float4 smem4[2048];          // 32 KB
    float* smem = (float*)smem4;

    if (blockIdx.x < GBLK) {
        // ---- gauss: block g owns u-columns [8g, 8g+8) for ALL 32 b ----
        int g = blockIdx.x;
        int u0 = g * 8;
        // stage Wq[:, u0..u0+8) into LDS: wslice[d*8 + j]
        for (int i = threadIdx.x; i < 2048; i += 256) {
            int d = i >> 1, h = i & 1;
            smem4[i] = *(const float4*)(Wq + (size_t)d * UU + u0 + h * 4);
        }
        __syncthreads();
        int b = threadIdx.x >> 3, ui = threadIdx.x & 7;
        const float* qb = query + (size_t)b * DD;
        float acc = 0.f;
#pragma unroll 8
        for (int d = 0; d < DD; ++d) acc += qb[d] * smem[d * 8 + ui];
        float val = tanhf(acc) * wp[u0 + ui];
        val += __shfl_xor(val, 1, 64);
        val += __shfl_xor(val, 2, 64);
        val += __shfl_xor(val, 4, 64);
        if (ui == 0) gpart[b * GBLK + g] = val;
        return;
    }

    // ---- flash: block = 128-row chunk; wave w owns row (4t + w), full 1024 d ----
    int fb = blockIdx.x - GBLK;
    int b = fb >> 5;               // / CHB
    int chunk = fb & (CHB - 1);
    int s0 = chunk * CHROWS;
    int w = threadIdx.x >> 6;
    int lane = threadIdx.x & 63;
    int tid = threadIdx.x;

    const float4* Q4 = (const float4*)query;
    float4 q0 = Q4[b * 256 + lane],       q1 = Q4[b * 256 + lane + 64],
           q2 = Q4[b * 256 + lane + 128], q3 = Q4[b * 256 + lane + 192];

    const char* gbase = (const char*)(keys + ((size_t)b * SS + s0) * DD);
    float4 a0 = {0,0,0,0}, a1 = {0,0,0,0}, a2 = {0,0,0,0}, a3 = {0,0,0,0};
    float m = -INFINITY, l = 0.f;

    // prologue: stage tile 0 into buffer 0 (16 KB, linear)
#pragma unroll
    for (int j = 0; j < 4; ++j)
        LOAD_LDS16(gbase + j * 4096 + tid * 16, (char*)smem + j * 4096 + tid * 16);

    int bf = 0;
    for (int t = 0; t < NT; ++t) {
        if (t + 1 < NT) {
            const char* gt = gbase + (size_t)(t + 1) * 16384;
            char* lb = (char*)smem + (bf ^ 1) * 16384;
#pragma unroll
            for (int j = 0; j < 4; ++j)
                LOAD_LDS16(gt + j * 4096 + tid * 16, lb + j * 4096 + tid * 16);
            asm volatile("s_waitcnt vmcnt(4)" ::: "memory");   // tile t landed; t+1 in flight
        } else {
            asm volatile("s_waitcnt vmcnt(0)" ::: "memory");
        }
        __builtin_amdgcn_s_barrier();                           // B1: tile t ready

        const float* rowp = smem + bf * 4096 + w * 1024;
        float4 k0 = *(const float4*)(rowp + (lane)       * 4);
        float4 k1 = *(const float4*)(rowp + (lane + 64)  * 4);
        float4 k2 = *(const float4*)(rowp + (lane + 128) * 4);
        float4 k3 = *(const float4*)(rowp + (lane + 192) * 4);

        float d = k0.x*q0.x + k0.y*q0.y + k0.z*q0.z + k0.w*q0.w
                + k1.x*q1.x + k1.y*q1.y + k1.z*q1.z + k1.w*q1.w
                + k2.x*q2.x + k2.y*q2.y + k2.z*q2.z + k2.w*q2.w
                + k3.x*q3.x + k3.y*q3.y + k3.z*q3.z + k3.w*q3.w;
#pragma unroll
        for (int o = 32; o > 0; o >>= 1) d += __shfl_xor(d, o, 64);

        if (lane == 0) scores[(size_t)b * SS + s0 + t * TROWS + w] = d;

        float mn = fmaxf(m, d);
        float corr = __expf(m - mn);   // exp(-inf) = 0 handles first tile
        float p = __expf(d - mn);
        l = l * corr + p;
        a0.x = a0.x*corr + p*k0.x; a0.y = a0.y*corr + p*k0.y; a0.z = a0.z*corr + p*k0.z; a0.w = a0.w*corr + p*k0.w;
        a1.x = a1.x*corr + p*k1.x; a1.y = a1.y*corr + p*k1.y; a1.z = a1.z*corr + p*k1.z; a1.w = a1.w*corr + p*k1.w;
        a2.x = a2.x*corr + p*k2.x; a2.y = a2.y*corr + p*k2.y; a2.z = a2.z*corr + p*k2.z; a2.w = a2.w*corr + p*k2.w;
        a3.x = a3.x*corr + p*k3.x; a3.y = a3.y*corr + p*k3.y; a3.z = a3.z*corr + p*k3.z; a3.w = a3.w*corr + p*k3.w;
        m = mn;

        __builtin_amdgcn_s_barrier();  // B2: release buf before next stage overwrites
        bf ^= 1;
    }

    // ---- block-level merge: 4 wave-partials -> 1 block-partial (reuse smem) ----
    if (lane == 0) { smem[4096 + w] = m; smem[4100 + w] = l; }
    __syncthreads();
    float M = fmaxf(fmaxf(smem[4096], smem[4097]), fmaxf(smem[4098], smem[4099]));
    float Ls = smem[4100] * __expf(smem[4096] - M) + smem[4101] * __expf(smem[4097] - M)
             + smem[4102] * __expf(smem[4098] - M) + smem[4103] * __expf(smem[4099] - M);
    float sw = __expf(m - M);
    float4* aw = (float4*)(smem + (size_t)w * 1024);
    float4 t0 = {a0.x*sw, a0.y*sw, a0.z*sw, a0.w*sw};
    float4 t1 = {a1.x*sw, a1.y*sw, a1.z*sw, a1.w*sw};
    float4 t2 = {a2.x*sw, a2.y*sw, a2.z*sw, a2.w*sw};
    float4 t3 = {a3.x*sw, a3.y*sw, a3.z*sw, a3.w*sw};
    __syncthreads();               // ensure M/Ls reads done before overwriting smem
    aw[lane] = t0; aw[lane + 64] = t1; aw[lane + 128] = t2; aw[lane + 192] = t3;
    __syncthreads();
    float4 s = {0,0,0,0};
#pragma unroll
    for (int w2 = 0; w2 < 4; ++w2) {
        float4 v = ((const float4*)(smem + (size_t)w2 * 1024))[tid];
        s.x += v.x; s.y += v.y; s.z += v.z; s.w += v.w;
    }
    ((float4*)(accbuf + (size_t)fb * DD))[tid] = s;
    if (tid == 0) { mlbuf[fb * 2] = M; mlbuf[fb * 2 + 1] = Ls; }
}

__global__ void combine_kernel(const float* __restrict__ mlbuf,
                               const float* __restrict__ accbuf,
                               const float* __restrict__ gpart,
                               const float* __restrict__ key_lengths,
                               const int* __restrict__ win,
                               float* __restrict__ ctx) {
    int b = blockIdx.x;          // grid (BB, 4)
    int d = blockIdx.y * 256 + threadIdx.x;

    __shared__ float red[128];
    __shared__ float mv[NPART], lv[NPART], wexp[NPART];

    if (threadIdx.x < 128) red[threadIdx.x] = gpart[b * GBLK + threadIdx.x];
    if (threadIdx.x < NPART) {
        mv[threadIdx.x] = mlbuf[(b * NPART + threadIdx.x) * 2];
        lv[threadIdx.x] = mlbuf[(b * NPART + threadIdx.x) * 2 + 1];
    }
    __syncthreads();
    for (int t = 64; t > 0; t >>= 1) {
        if (threadIdx.x < t) red[threadIdx.x] += red[threadIdx.x + t];
        __syncthreads();
    }
    float presig = red[0];

    float M = -INFINITY;
#pragma unroll
    for (int i = 0; i < NPART; ++i) M = fmaxf(M, mv[i]);
    float L = 0.f;
#pragma unroll
    for (int i = 0; i < NPART; ++i) L += lv[i] * __expf(mv[i] - M);
    __syncthreads();
    if (threadIdx.x < NPART) wexp[threadIdx.x] = __expf(mv[threadIdx.x] - M);
    __syncthreads();

    float acc = 0.f;
#pragma unroll 8
    for (int i = 0; i < NPART; ++i)
        acc += wexp[i] * accbuf[((size_t)b * NPART + i) * DD + d];

    float sig = 1.f / (1.f + __expf(-presig));
    float kl = key_lengths[b];
    float pa = kl * sig;
    float wv = (float)(*win);
    float std2 = (wv * 0.5f) * (wv * 0.5f);
    float g = __expf(-((kl - pa) * (kl - pa)) / (2.f * std2));

    ctx[(size_t)b * DD + d] = acc * g / L;
}

extern "C" void kernel_launch(void* const* d_in, const int* in_sizes, int n_in,
                              void* d_out, int out_size, void* d_ws, size_t ws_size,
                              hipStream_t stream) {
    const float* query       = (const float*)d_in[0];
    const float* keys        = (const float*)d_in[1];
    const float* key_lengths = (const float*)d_in[2];
    const float* Wq          = (const float*)d_in[3];
    const float* wp          = (const float*)d_in[4];
    const int*   win         = (const int*)d_in[5];

    float* out    = (float*)d_out;
    float* ctx    = out;            // B*D floats
    float* scores = out + BB * DD;  // B*S floats
    float* wsbuf  = (float*)d_ws;
    float* gpart  = wsbuf;          // 4096 floats
    float* mlbuf  = wsbuf + 4096;   // FBLK*2 floats
    float* accbuf = wsbuf + 8192;   // FBLK*DD floats (4 MiB)

    fused_kernel<<<FBLK + GBLK, 256, 0, stream>>>(query, keys, Wq, wp,
                                                  scores, mlbuf, accbuf, gpart);

    dim3 cgrid(BB, DD / 256);
    combine_kernel<<<cgrid, 256, 0, stream>>>(mlbuf, accbuf, gpart, key_lengths, win, ctx);
}